// Round 1
// baseline (580.358 us; speedup 1.0000x reference)
//
#include <hip/hip_runtime.h>
#include <math.h>

#define NN 512
#define RR 262144  // NN*NN
#define EPS_F 1e-5f

typedef unsigned short u16;
typedef unsigned int u32;
typedef __bf16 bf16x8 __attribute__((ext_vector_type(8)));
typedef float f32x4 __attribute__((ext_vector_type(4)));

__device__ __forceinline__ u16 f2bs(float f) {
  __bf16 h = (__bf16)f;
  return __builtin_bit_cast(u16, h);
}
__device__ __forceinline__ float bs2f(u16 u) {
  return (float)__builtin_bit_cast(__bf16, u);
}
__device__ __forceinline__ float sigmoidf_(float x) {
  return 1.f / (1.f + __expf(-x));
}

// ---------------- Kernel A: LayerNorm(z) -> zn (bf16) ----------------
// wave per row: 64 lanes x 2 floats
__global__ __launch_bounds__(256) void k_ln_in(const float* __restrict__ z,
                                               const float* __restrict__ g,
                                               const float* __restrict__ b,
                                               u16* __restrict__ zn) {
  const int w = threadIdx.x >> 6, l = threadIdx.x & 63;
  const long r = (long)blockIdx.x * 4 + w;
  const float2 v = *(const float2*)(z + r * 128 + l * 2);
  float s = v.x + v.y, sq = v.x * v.x + v.y * v.y;
#pragma unroll
  for (int m = 1; m < 64; m <<= 1) {
    s += __shfl_xor(s, m);
    sq += __shfl_xor(sq, m);
  }
  const float mu = s * 0.0078125f;
  const float var = sq * 0.0078125f - mu * mu;
  const float rs = rsqrtf(var + EPS_F);
  const float2 gg = *(const float2*)(g + l * 2);
  const float2 bb = *(const float2*)(b + l * 2);
  const u32 o = (u32)f2bs((v.x - mu) * rs * gg.x + bb.x) |
                ((u32)f2bs((v.y - mu) * rs * gg.y + bb.y) << 16);
  *(u32*)(zn + r * 128 + l * 2) = o;
}

// ---------------- Kernel B: projections ----------------
// grid (R/128, 5). tiles tt=0..3: 128 rows x 64 h of (p,gate) interleaved
// at 16-col granularity -> a_t/b_t [h][r] bf16 (LDS transpose).
// tt=4: g = sigmoid(zn@w_g + b_g) -> [r][d] bf16.
__global__ __launch_bounds__(256) void k_proj(
    const u16* __restrict__ zn, const float* __restrict__ mask,
    const float* __restrict__ w_ab_p, const float* __restrict__ b_ab_p,
    const float* __restrict__ w_ab_g, const float* __restrict__ b_ab_g,
    const float* __restrict__ w_g, const float* __restrict__ b_g,
    u16* __restrict__ a_t, u16* __restrict__ b_t, u16* __restrict__ g_out) {
  __shared__ __align__(16) u16 As[128 * 136];
  __shared__ __align__(16) u16 Bs[128 * 136];
  __shared__ float maskS[128];
  const int t = threadIdx.x;
  const int tt = blockIdx.y;
  const long row0 = (long)blockIdx.x * 128;

  {  // stage zn tile [128 r][128 k]
    const int row = t >> 1, half = t & 1;
    const uint4* src = (const uint4*)(zn + (row0 + row) * 128 + half * 64);
    uint4* dst = (uint4*)(As + row * 136 + half * 64);
#pragma unroll
    for (int i = 0; i < 8; ++i) dst[i] = src[i];
  }
  {  // stage weights fp32->bf16, interleaved p/gate rows
    const int n = t >> 1, half = t & 1;
    const float* src;
    if (tt < 4) {
      const int srow = tt * 64 + ((n >> 5) << 4) + (n & 15);
      src = (((n >> 4) & 1) ? w_ab_g : w_ab_p) + srow * 128 + half * 64;
    } else {
      src = w_g + n * 128 + half * 64;
    }
    u16* dst = Bs + n * 136 + half * 64;
#pragma unroll
    for (int i = 0; i < 16; ++i) {
      const float4 v = *(const float4*)(src + i * 4);
      dst[i * 4 + 0] = f2bs(v.x);
      dst[i * 4 + 1] = f2bs(v.y);
      dst[i * 4 + 2] = f2bs(v.z);
      dst[i * 4 + 3] = f2bs(v.w);
    }
  }
  if (t < 128) maskS[t] = mask[row0 + t];
  __syncthreads();

  const int lane = t & 63, wv = t >> 6;
  const int quad = lane >> 4, tl = lane & 15;
  const int wm = wv >> 1, wn = wv & 1;
  f32x4 acc[4][4];
#pragma unroll
  for (int mt = 0; mt < 4; ++mt)
#pragma unroll
    for (int nt = 0; nt < 4; ++nt) acc[mt][nt] = (f32x4){0.f, 0.f, 0.f, 0.f};

#pragma unroll
  for (int ks = 0; ks < 4; ++ks) {
    bf16x8 af[4], bfr[4];
#pragma unroll
    for (int mt = 0; mt < 4; ++mt)
      af[mt] = *(const bf16x8*)(As + (wm * 64 + mt * 16 + tl) * 136 + ks * 32 + quad * 8);
#pragma unroll
    for (int nt = 0; nt < 4; ++nt)
      bfr[nt] = *(const bf16x8*)(Bs + (wn * 64 + nt * 16 + tl) * 136 + ks * 32 + quad * 8);
#pragma unroll
    for (int mt = 0; mt < 4; ++mt)
#pragma unroll
      for (int nt = 0; nt < 4; ++nt)
        acc[mt][nt] = __builtin_amdgcn_mfma_f32_16x16x32_bf16(af[mt], bfr[nt], acc[mt][nt], 0, 0, 0);
  }

  if (tt < 4) {
    __syncthreads();  // done reading As; reuse as transpose buffer
    u16* trans = As;  // [64 h][stride 136] r
#pragma unroll
    for (int b2 = 0; b2 < 2; ++b2) {
      const int hl = wn * 32 + b2 * 16 + tl;
      const int hg = tt * 64 + hl;
      const float bp = b_ab_p[hg], bg = b_ab_g[hg];
#pragma unroll
      for (int mt = 0; mt < 4; ++mt) {
#pragma unroll
        for (int rg = 0; rg < 4; ++rg) {
          const int r = wm * 64 + mt * 16 + quad * 4 + rg;
          const float p = acc[mt][2 * b2][rg] + bp;
          const float gt = acc[mt][2 * b2 + 1][rg] + bg;
          trans[hl * 136 + r] = f2bs(sigmoidf_(gt) * maskS[r] * p);
        }
      }
    }
    __syncthreads();
    const int hl = t >> 2, qq = t & 3;
    const int hg = tt * 64 + hl;
    u16* dbuf = (tt < 2) ? a_t : b_t;
    const int hb = (tt < 2) ? hg : hg - 128;
    const uint4* src = (const uint4*)(trans + hl * 136 + qq * 32);
    uint4* dst = (uint4*)(dbuf + (long)hb * RR + row0 + qq * 32);
#pragma unroll
    for (int i = 0; i < 4; ++i) dst[i] = src[i];
  } else {
#pragma unroll
    for (int nt = 0; nt < 4; ++nt) {
      const int c = wn * 64 + nt * 16 + tl;
      const float bgc = b_g[c];
#pragma unroll
      for (int mt = 0; mt < 4; ++mt)
#pragma unroll
        for (int rg = 0; rg < 4; ++rg) {
          const int r = wm * 64 + mt * 16 + quad * 4 + rg;
          g_out[(row0 + r) * (long)128 + c] = f2bs(sigmoidf_(acc[mt][nt][rg] + bgc));
        }
    }
  }
}

// ---------------- Kernel C: triangle einsum ----------------
// per h: X_h = A_h * B_h^T (512x512x512), 128x128 tile per block, BK=64
__global__ __launch_bounds__(256) void k_tri(const u16* __restrict__ a_t,
                                             const u16* __restrict__ b_t,
                                             u16* __restrict__ x_t) {
  __shared__ __align__(16) u16 As[128 * 72];
  __shared__ __align__(16) u16 Bs[128 * 72];
  const int t = threadIdx.x;
  const int h = blockIdx.y;
  const int i0 = (blockIdx.x >> 2) * 128, j0 = (blockIdx.x & 3) * 128;
  const u16* Ag = a_t + (long)h * RR;
  const u16* Bg = b_t + (long)h * RR;
  const int lane = t & 63, wv = t >> 6;
  const int quad = lane >> 4, tl = lane & 15;
  const int wm = wv >> 1, wn = wv & 1;
  const int chunk = t & 7, rb = t >> 3;

  f32x4 acc[4][4];
#pragma unroll
  for (int mt = 0; mt < 4; ++mt)
#pragma unroll
    for (int nt = 0; nt < 4; ++nt) acc[mt][nt] = (f32x4){0.f, 0.f, 0.f, 0.f};

  for (int kt = 0; kt < 8; ++kt) {
    __syncthreads();
#pragma unroll
    for (int p = 0; p < 4; ++p) {
      const int row = rb + p * 32;
      *(uint4*)(As + row * 72 + chunk * 8) =
          *(const uint4*)(Ag + (long)(i0 + row) * 512 + kt * 64 + chunk * 8);
      *(uint4*)(Bs + row * 72 + chunk * 8) =
          *(const uint4*)(Bg + (long)(j0 + row) * 512 + kt * 64 + chunk * 8);
    }
    __syncthreads();
#pragma unroll
    for (int ks = 0; ks < 2; ++ks) {
      bf16x8 af[4], bfr[4];
#pragma unroll
      for (int mt = 0; mt < 4; ++mt)
        af[mt] = *(const bf16x8*)(As + (wm * 64 + mt * 16 + tl) * 72 + ks * 32 + quad * 8);
#pragma unroll
      for (int nt = 0; nt < 4; ++nt)
        bfr[nt] = *(const bf16x8*)(Bs + (wn * 64 + nt * 16 + tl) * 72 + ks * 32 + quad * 8);
#pragma unroll
      for (int mt = 0; mt < 4; ++mt)
#pragma unroll
        for (int nt = 0; nt < 4; ++nt)
          acc[mt][nt] = __builtin_amdgcn_mfma_f32_16x16x32_bf16(af[mt], bfr[nt], acc[mt][nt], 0, 0, 0);
    }
  }
#pragma unroll
  for (int mt = 0; mt < 4; ++mt)
#pragma unroll
    for (int nt = 0; nt < 4; ++nt)
#pragma unroll
      for (int rg = 0; rg < 4; ++rg) {
        const int i = i0 + wm * 64 + mt * 16 + quad * 4 + rg;
        const int j = j0 + wn * 64 + nt * 16 + tl;
        x_t[(long)h * RR + (long)i * 512 + j] = f2bs(acc[mt][nt][rg]);
      }
}

// ---------------- Kernel D: LN(x) + x@w_z^T + b_z, * gate ----------------
__global__ __launch_bounds__(256) void k_out(const u16* __restrict__ x_t,
                                             const float* __restrict__ w_z,
                                             const float* __restrict__ b_z,
                                             const float* __restrict__ ln_g,
                                             const float* __restrict__ ln_b,
                                             const u16* __restrict__ g_in,
                                             float* __restrict__ out) {
  __shared__ __align__(16) u16 Xs[128 * 136];
  __shared__ __align__(16) u16 Ws[128 * 136];
  __shared__ float lnGs[128], lnBs[128];
  const int t = threadIdx.x;
  const long row0 = (long)blockIdx.x * 128;

  if (t < 128) {
    lnGs[t] = ln_g[t];
    lnBs[t] = ln_b[t];
  }
  {  // stage X transposed: x_t[h][r] -> Xs[r][h]
    const int hb = t >> 3, rq = t & 7;
    u32 xv[4][8];
#pragma unroll
    for (int hh = 0; hh < 4; ++hh) {
      const uint4* src = (const uint4*)(x_t + (long)(hb * 4 + hh) * RR + row0 + rq * 16);
      const uint4 a = src[0], b = src[1];
      xv[hh][0] = a.x; xv[hh][1] = a.y; xv[hh][2] = a.z; xv[hh][3] = a.w;
      xv[hh][4] = b.x; xv[hh][5] = b.y; xv[hh][6] = b.z; xv[hh][7] = b.w;
    }
#pragma unroll
    for (int rr = 0; rr < 16; ++rr) {
      const int wi = rr >> 1, sh = (rr & 1) * 16;
      const u32 e0 = (xv[0][wi] >> sh) & 0xffffu;
      const u32 e1 = (xv[1][wi] >> sh) & 0xffffu;
      const u32 e2 = (xv[2][wi] >> sh) & 0xffffu;
      const u32 e3 = (xv[3][wi] >> sh) & 0xffffu;
      *(uint2*)(Xs + (rq * 16 + rr) * 136 + hb * 4) = make_uint2(e0 | (e1 << 16), e2 | (e3 << 16));
    }
  }
  {  // stage w_z fp32->bf16
    const int n = t >> 1, half = t & 1;
    const float* src = w_z + n * 128 + half * 64;
    u16* dst = Ws + n * 136 + half * 64;
#pragma unroll
    for (int i = 0; i < 16; ++i) {
      const float4 v = *(const float4*)(src + i * 4);
      dst[i * 4 + 0] = f2bs(v.x);
      dst[i * 4 + 1] = f2bs(v.y);
      dst[i * 4 + 2] = f2bs(v.z);
      dst[i * 4 + 3] = f2bs(v.w);
    }
  }
  __syncthreads();
  {  // LayerNorm over h, 2 threads per row
    const int r = t >> 1, half = t & 1;
    u16* xr = Xs + r * 136 + half * 64;
    float vals[64];
    float s = 0.f, sq = 0.f;
#pragma unroll
    for (int i = 0; i < 64; ++i) {
      const float v = bs2f(xr[i]);
      vals[i] = v;
      s += v;
      sq += v * v;
    }
    s += __shfl_xor(s, 1);
    sq += __shfl_xor(sq, 1);
    const float mu = s * 0.0078125f;
    const float var = sq * 0.0078125f - mu * mu;
    const float rs = rsqrtf(var + EPS_F);
#pragma unroll
    for (int i = 0; i < 64; ++i) {
      const int hh = half * 64 + i;
      xr[i] = f2bs((vals[i] - mu) * rs * lnGs[hh] + lnBs[hh]);
    }
  }
  __syncthreads();

  const int lane = t & 63, wv = t >> 6;
  const int quad = lane >> 4, tl = lane & 15;
  const int wm = wv >> 1, wn = wv & 1;
  f32x4 acc[4][4];
#pragma unroll
  for (int mt = 0; mt < 4; ++mt)
#pragma unroll
    for (int nt = 0; nt < 4; ++nt) acc[mt][nt] = (f32x4){0.f, 0.f, 0.f, 0.f};

#pragma unroll
  for (int ks = 0; ks < 4; ++ks) {
    bf16x8 af[4], bfr[4];
#pragma unroll
    for (int mt = 0; mt < 4; ++mt)
      af[mt] = *(const bf16x8*)(Xs + (wm * 64 + mt * 16 + tl) * 136 + ks * 32 + quad * 8);
#pragma unroll
    for (int nt = 0; nt < 4; ++nt)
      bfr[nt] = *(const bf16x8*)(Ws + (wn * 64 + nt * 16 + tl) * 136 + ks * 32 + quad * 8);
#pragma unroll
    for (int mt = 0; mt < 4; ++mt)
#pragma unroll
      for (int nt = 0; nt < 4; ++nt)
        acc[mt][nt] = __builtin_amdgcn_mfma_f32_16x16x32_bf16(af[mt], bfr[nt], acc[mt][nt], 0, 0, 0);
  }
#pragma unroll
  for (int nt = 0; nt < 4; ++nt) {
    const int c = wn * 64 + nt * 16 + tl;
    const float bz = b_z[c];
#pragma unroll
    for (int mt = 0; mt < 4; ++mt)
#pragma unroll
      for (int rg = 0; rg < 4; ++rg) {
        const int r = wm * 64 + mt * 16 + quad * 4 + rg;
        const long idx = (row0 + r) * 128 + c;
        out[idx] = (acc[mt][nt][rg] + bz) * bs2f(g_in[idx]);
      }
  }
}

extern "C" void kernel_launch(void* const* d_in, const int* in_sizes, int n_in,
                              void* d_out, int out_size, void* d_ws, size_t ws_size,
                              hipStream_t stream) {
  const float* z = (const float*)d_in[0];
  const float* mask = (const float*)d_in[1];
  const float* w_ab_p = (const float*)d_in[2];
  const float* b_ab_p = (const float*)d_in[3];
  const float* w_ab_g = (const float*)d_in[4];
  const float* b_ab_g = (const float*)d_in[5];
  const float* w_g = (const float*)d_in[6];
  const float* b_g = (const float*)d_in[7];
  const float* w_z = (const float*)d_in[8];
  const float* b_z = (const float*)d_in[9];
  const float* ln_in_g = (const float*)d_in[10];
  const float* ln_in_b = (const float*)d_in[11];
  const float* ln_out_g = (const float*)d_in[12];
  const float* ln_out_b = (const float*)d_in[13];
  float* out = (float*)d_out;

  // workspace layout (all bf16 u16): zn, a_t, b_t, x_t, g  (5 * 64 MB = 320 MB)
  u16* zn = (u16*)d_ws;
  u16* a_t = zn + (size_t)RR * 128;
  u16* b_t = a_t + (size_t)RR * 128;
  u16* x_t = b_t + (size_t)RR * 128;
  u16* g_b = x_t + (size_t)RR * 128;

  k_ln_in<<<RR / 4, 256, 0, stream>>>(z, ln_in_g, ln_in_b, zn);
  k_proj<<<dim3(RR / 128, 5), 256, 0, stream>>>(zn, mask, w_ab_p, b_ab_p, w_ab_g,
                                                b_ab_g, w_g, b_g, a_t, b_t, g_b);
  k_tri<<<dim3(16, 128), 256, 0, stream>>>(a_t, b_t, x_t);
  k_out<<<RR / 128, 256, 0, stream>>>(x_t, w_z, b_z, ln_out_g, ln_out_b, g_b, out);
}

// Round 2
// 577.676 us; speedup vs baseline: 1.0046x; 1.0046x over previous
//
#include <hip/hip_runtime.h>
#include <math.h>

#define NN 512
#define RR 262144  // NN*NN
#define EPS_F 1e-5f

typedef unsigned short u16;
typedef unsigned int u32;
typedef __bf16 bf16x8 __attribute__((ext_vector_type(8)));
typedef float f32x4 __attribute__((ext_vector_type(4)));

__device__ __forceinline__ u16 f2bs(float f) {
  __bf16 h = (__bf16)f;
  return __builtin_bit_cast(u16, h);
}
__device__ __forceinline__ float bs2f(u16 u) {
  return (float)__builtin_bit_cast(__bf16, u);
}
__device__ __forceinline__ float sigmoidf_(float x) {
  return 1.f / (1.f + __expf(-x));
}

// ---------------- Kernel W: one-shot weight convert fp32->bf16 ----------------
// wb rows 0..511: 4 tiles of 128 rows, p/gate interleaved at 16-row granularity
// (row n in tile tt sources srow = tt*64 + ((n>>5)<<4) + (n&15) of w_ab_p or
// w_ab_g depending on bit4 of n). rows 512..639: w_g.
__global__ __launch_bounds__(256) void k_wconv(const float* __restrict__ w_ab_p,
                                               const float* __restrict__ w_ab_g,
                                               const float* __restrict__ w_g,
                                               u16* __restrict__ wb) {
  const int u = blockIdx.x * 256 + threadIdx.x;  // 0..20479
  const int row = u >> 5;                        // 0..639
  const int c4 = (u & 31) * 4;
  const float* src;
  if (row < 512) {
    const int tt = row >> 7, n = row & 127;
    const int srow = tt * 64 + ((n >> 5) << 4) + (n & 15);
    src = (((n >> 4) & 1) ? w_ab_g : w_ab_p) + srow * 128 + c4;
  } else {
    src = w_g + (row - 512) * 128 + c4;
  }
  const float4 v = *(const float4*)src;
  u16 o[4] = {f2bs(v.x), f2bs(v.y), f2bs(v.z), f2bs(v.w)};
  *(uint2*)(wb + row * 128 + c4) = *(uint2*)o;
}

// ---------------- Kernel B: fused LN(z) + all projections ----------------
// grid R/128. Per block: LN 128 rows of z into LDS (bf16), then loop 5 weight
// tiles: stage bf16 weights (uint4), 64 MFMAs, epilogue (a/b: gate*mask*p,
// LDS transpose to [h][r]; gate tile: sigmoid, direct store).
__global__ __launch_bounds__(256) void k_proj(
    const float* __restrict__ z, const float* __restrict__ mask,
    const u16* __restrict__ wb, const float* __restrict__ b_ab_p,
    const float* __restrict__ b_ab_g, const float* __restrict__ b_g,
    const float* __restrict__ ln_g, const float* __restrict__ ln_b,
    u16* __restrict__ a_t, u16* __restrict__ b_t, u16* __restrict__ g_out) {
  __shared__ __align__(16) u16 As[128 * 136];
  __shared__ __align__(16) u16 Bs[128 * 136];
  __shared__ float maskS[128];
  const int t = threadIdx.x;
  const long row0 = (long)blockIdx.x * 128;

  {  // fused input LayerNorm: z fp32 -> bf16 zn tile in As. 2 threads/row.
    const int row = t >> 1, half = t & 1;
    const float* zr = z + (row0 + row) * 128 + half * 64;
    float vals[64];
    float s = 0.f, sq = 0.f;
#pragma unroll
    for (int i = 0; i < 16; ++i) {
      const float4 v = *(const float4*)(zr + i * 4);
      vals[i * 4 + 0] = v.x;
      vals[i * 4 + 1] = v.y;
      vals[i * 4 + 2] = v.z;
      vals[i * 4 + 3] = v.w;
      s += v.x + v.y + v.z + v.w;
      sq += v.x * v.x + v.y * v.y + v.z * v.z + v.w * v.w;
    }
    s += __shfl_xor(s, 1);
    sq += __shfl_xor(sq, 1);
    const float mu = s * 0.0078125f;
    const float var = sq * 0.0078125f - mu * mu;
    const float rs = rsqrtf(var + EPS_F);
    u16 ob[64];
#pragma unroll
    for (int i = 0; i < 16; ++i) {
      const float4 gg = *(const float4*)(ln_g + half * 64 + i * 4);
      const float4 bb = *(const float4*)(ln_b + half * 64 + i * 4);
      ob[i * 4 + 0] = f2bs((vals[i * 4 + 0] - mu) * rs * gg.x + bb.x);
      ob[i * 4 + 1] = f2bs((vals[i * 4 + 1] - mu) * rs * gg.y + bb.y);
      ob[i * 4 + 2] = f2bs((vals[i * 4 + 2] - mu) * rs * gg.z + bb.z);
      ob[i * 4 + 3] = f2bs((vals[i * 4 + 3] - mu) * rs * gg.w + bb.w);
    }
    uint4* dst = (uint4*)(As + row * 136 + half * 64);
    const uint4* sp = (const uint4*)ob;
#pragma unroll
    for (int i = 0; i < 8; ++i) dst[i] = sp[i];
  }
  if (t < 128) maskS[t] = mask[row0 + t];

  const int lane = t & 63, wv = t >> 6;
  const int quad = lane >> 4, tl = lane & 15;
  const int wm = wv >> 1, wn = wv & 1;

  for (int tt = 0; tt < 5; ++tt) {
    {  // stage weight tile (already bf16), coalesced uint4
      const int n = t >> 1, half = t & 1;
      const uint4* src = (const uint4*)(wb + (tt * 128 + n) * 128 + half * 64);
      uint4* dst = (uint4*)(Bs + n * 136 + half * 64);
#pragma unroll
      for (int i = 0; i < 8; ++i) dst[i] = src[i];
    }
    __syncthreads();

    f32x4 acc[4][4];
#pragma unroll
    for (int mt = 0; mt < 4; ++mt)
#pragma unroll
      for (int nt = 0; nt < 4; ++nt) acc[mt][nt] = (f32x4){0.f, 0.f, 0.f, 0.f};

#pragma unroll
    for (int ks = 0; ks < 4; ++ks) {
      bf16x8 af[4], bfr[4];
#pragma unroll
      for (int mt = 0; mt < 4; ++mt)
        af[mt] = *(const bf16x8*)(As + (wm * 64 + mt * 16 + tl) * 136 + ks * 32 + quad * 8);
#pragma unroll
      for (int nt = 0; nt < 4; ++nt)
        bfr[nt] = *(const bf16x8*)(Bs + (wn * 64 + nt * 16 + tl) * 136 + ks * 32 + quad * 8);
#pragma unroll
      for (int mt = 0; mt < 4; ++mt)
#pragma unroll
        for (int nt = 0; nt < 4; ++nt)
          acc[mt][nt] = __builtin_amdgcn_mfma_f32_16x16x32_bf16(af[mt], bfr[nt], acc[mt][nt], 0, 0, 0);
    }
    __syncthreads();  // fragment reads of Bs done

    if (tt < 4) {
      // gate*mask*p, transpose into Bs as [64 h][stride 136] r
#pragma unroll
      for (int b2 = 0; b2 < 2; ++b2) {
        const int hl = wn * 32 + b2 * 16 + tl;
        const int hg = tt * 64 + hl;
        const float bp = b_ab_p[hg], bg = b_ab_g[hg];
#pragma unroll
        for (int mt = 0; mt < 4; ++mt)
#pragma unroll
          for (int rg = 0; rg < 4; ++rg) {
            const int r = wm * 64 + mt * 16 + quad * 4 + rg;
            const float p = acc[mt][2 * b2][rg] + bp;
            const float gt = acc[mt][2 * b2 + 1][rg] + bg;
            Bs[hl * 136 + r] = f2bs(sigmoidf_(gt) * maskS[r] * p);
          }
      }
      __syncthreads();
      {
        const int hl = t >> 2, qq = t & 3;
        const int hg = tt * 64 + hl;
        u16* dbuf = (tt < 2) ? a_t : b_t;
        const int hb = (tt < 2) ? hg : hg - 128;
        const uint4* src = (const uint4*)(Bs + hl * 136 + qq * 32);
        uint4* dst = (uint4*)(dbuf + (long)hb * RR + row0 + qq * 32);
#pragma unroll
        for (int i = 0; i < 4; ++i) dst[i] = src[i];
      }
      __syncthreads();  // store reads of Bs done before next tt restages
    } else {
#pragma unroll
      for (int nt = 0; nt < 4; ++nt) {
        const int c = wn * 64 + nt * 16 + tl;
        const float bgc = b_g[c];
#pragma unroll
        for (int mt = 0; mt < 4; ++mt)
#pragma unroll
          for (int rg = 0; rg < 4; ++rg) {
            const int r = wm * 64 + mt * 16 + quad * 4 + rg;
            g_out[(row0 + r) * (long)128 + c] = f2bs(sigmoidf_(acc[mt][nt][rg] + bgc));
          }
      }
    }
  }
}

// ---------------- Kernel C: triangle einsum ----------------
// per h: X_h = A_h * B_h^T (512x512x512), 128x128 tile per block, BK=64
__global__ __launch_bounds__(256) void k_tri(const u16* __restrict__ a_t,
                                             const u16* __restrict__ b_t,
                                             u16* __restrict__ x_t) {
  __shared__ __align__(16) u16 As[128 * 72];
  __shared__ __align__(16) u16 Bs[128 * 72];
  const int t = threadIdx.x;
  const int h = blockIdx.y;
  const int i0 = (blockIdx.x >> 2) * 128, j0 = (blockIdx.x & 3) * 128;
  const u16* Ag = a_t + (long)h * RR;
  const u16* Bg = b_t + (long)h * RR;
  const int lane = t & 63, wv = t >> 6;
  const int quad = lane >> 4, tl = lane & 15;
  const int wm = wv >> 1, wn = wv & 1;
  const int chunk = t & 7, rb = t >> 3;

  f32x4 acc[4][4];
#pragma unroll
  for (int mt = 0; mt < 4; ++mt)
#pragma unroll
    for (int nt = 0; nt < 4; ++nt) acc[mt][nt] = (f32x4){0.f, 0.f, 0.f, 0.f};

  for (int kt = 0; kt < 8; ++kt) {
    __syncthreads();
#pragma unroll
    for (int p = 0; p < 4; ++p) {
      const int row = rb + p * 32;
      *(uint4*)(As + row * 72 + chunk * 8) =
          *(const uint4*)(Ag + (long)(i0 + row) * 512 + kt * 64 + chunk * 8);
      *(uint4*)(Bs + row * 72 + chunk * 8) =
          *(const uint4*)(Bg + (long)(j0 + row) * 512 + kt * 64 + chunk * 8);
    }
    __syncthreads();
#pragma unroll
    for (int ks = 0; ks < 2; ++ks) {
      bf16x8 af[4], bfr[4];
#pragma unroll
      for (int mt = 0; mt < 4; ++mt)
        af[mt] = *(const bf16x8*)(As + (wm * 64 + mt * 16 + tl) * 72 + ks * 32 + quad * 8);
#pragma unroll
      for (int nt = 0; nt < 4; ++nt)
        bfr[nt] = *(const bf16x8*)(Bs + (wn * 64 + nt * 16 + tl) * 72 + ks * 32 + quad * 8);
#pragma unroll
      for (int mt = 0; mt < 4; ++mt)
#pragma unroll
        for (int nt = 0; nt < 4; ++nt)
          acc[mt][nt] = __builtin_amdgcn_mfma_f32_16x16x32_bf16(af[mt], bfr[nt], acc[mt][nt], 0, 0, 0);
    }
  }
#pragma unroll
  for (int mt = 0; mt < 4; ++mt)
#pragma unroll
    for (int nt = 0; nt < 4; ++nt)
#pragma unroll
      for (int rg = 0; rg < 4; ++rg) {
        const int i = i0 + wm * 64 + mt * 16 + quad * 4 + rg;
        const int j = j0 + wn * 64 + nt * 16 + tl;
        x_t[(long)h * RR + (long)i * 512 + j] = f2bs(acc[mt][nt][rg]);
      }
}

// ---------------- Kernel D: LN(x) + x@w_z^T + b_z, * gate ----------------
__global__ __launch_bounds__(256) void k_out(const u16* __restrict__ x_t,
                                             const float* __restrict__ w_z,
                                             const float* __restrict__ b_z,
                                             const float* __restrict__ ln_g,
                                             const float* __restrict__ ln_b,
                                             const u16* __restrict__ g_in,
                                             float* __restrict__ out) {
  __shared__ __align__(16) u16 Xs[128 * 136];
  __shared__ __align__(16) u16 Ws[128 * 136];
  __shared__ float lnGs[128], lnBs[128];
  const int t = threadIdx.x;
  const long row0 = (long)blockIdx.x * 128;

  if (t < 128) {
    lnGs[t] = ln_g[t];
    lnBs[t] = ln_b[t];
  }
  {  // stage X transposed: x_t[h][r] -> Xs[r][h]
    const int hb = t >> 3, rq = t & 7;
    u32 xv[4][8];
#pragma unroll
    for (int hh = 0; hh < 4; ++hh) {
      const uint4* src = (const uint4*)(x_t + (long)(hb * 4 + hh) * RR + row0 + rq * 16);
      const uint4 a = src[0], b = src[1];
      xv[hh][0] = a.x; xv[hh][1] = a.y; xv[hh][2] = a.z; xv[hh][3] = a.w;
      xv[hh][4] = b.x; xv[hh][5] = b.y; xv[hh][6] = b.z; xv[hh][7] = b.w;
    }
#pragma unroll
    for (int rr = 0; rr < 16; ++rr) {
      const int wi = rr >> 1, sh = (rr & 1) * 16;
      const u32 e0 = (xv[0][wi] >> sh) & 0xffffu;
      const u32 e1 = (xv[1][wi] >> sh) & 0xffffu;
      const u32 e2 = (xv[2][wi] >> sh) & 0xffffu;
      const u32 e3 = (xv[3][wi] >> sh) & 0xffffu;
      *(uint2*)(Xs + (rq * 16 + rr) * 136 + hb * 4) = make_uint2(e0 | (e1 << 16), e2 | (e3 << 16));
    }
  }
  {  // stage w_z fp32->bf16
    const int n = t >> 1, half = t & 1;
    const float* src = w_z + n * 128 + half * 64;
    u16* dst = Ws + n * 136 + half * 64;
#pragma unroll
    for (int i = 0; i < 16; ++i) {
      const float4 v = *(const float4*)(src + i * 4);
      dst[i * 4 + 0] = f2bs(v.x);
      dst[i * 4 + 1] = f2bs(v.y);
      dst[i * 4 + 2] = f2bs(v.z);
      dst[i * 4 + 3] = f2bs(v.w);
    }
  }
  __syncthreads();
  {  // LayerNorm over h, 2 threads per row
    const int r = t >> 1, half = t & 1;
    u16* xr = Xs + r * 136 + half * 64;
    float vals[64];
    float s = 0.f, sq = 0.f;
#pragma unroll
    for (int i = 0; i < 64; ++i) {
      const float v = bs2f(xr[i]);
      vals[i] = v;
      s += v;
      sq += v * v;
    }
    s += __shfl_xor(s, 1);
    sq += __shfl_xor(sq, 1);
    const float mu = s * 0.0078125f;
    const float var = sq * 0.0078125f - mu * mu;
    const float rs = rsqrtf(var + EPS_F);
#pragma unroll
    for (int i = 0; i < 64; ++i) {
      const int hh = half * 64 + i;
      xr[i] = f2bs((vals[i] - mu) * rs * lnGs[hh] + lnBs[hh]);
    }
  }
  __syncthreads();

  const int lane = t & 63, wv = t >> 6;
  const int quad = lane >> 4, tl = lane & 15;
  const int wm = wv >> 1, wn = wv & 1;
  f32x4 acc[4][4];
#pragma unroll
  for (int mt = 0; mt < 4; ++mt)
#pragma unroll
    for (int nt = 0; nt < 4; ++nt) acc[mt][nt] = (f32x4){0.f, 0.f, 0.f, 0.f};

#pragma unroll
  for (int ks = 0; ks < 4; ++ks) {
    bf16x8 af[4], bfr[4];
#pragma unroll
    for (int mt = 0; mt < 4; ++mt)
      af[mt] = *(const bf16x8*)(Xs + (wm * 64 + mt * 16 + tl) * 136 + ks * 32 + quad * 8);
#pragma unroll
    for (int nt = 0; nt < 4; ++nt)
      bfr[nt] = *(const bf16x8*)(Ws + (wn * 64 + nt * 16 + tl) * 136 + ks * 32 + quad * 8);
#pragma unroll
    for (int mt = 0; mt < 4; ++mt)
#pragma unroll
      for (int nt = 0; nt < 4; ++nt)
        acc[mt][nt] = __builtin_amdgcn_mfma_f32_16x16x32_bf16(af[mt], bfr[nt], acc[mt][nt], 0, 0, 0);
  }
#pragma unroll
  for (int nt = 0; nt < 4; ++nt) {
    const int c = wn * 64 + nt * 16 + tl;
    const float bz = b_z[c];
#pragma unroll
    for (int mt = 0; mt < 4; ++mt)
#pragma unroll
      for (int rg = 0; rg < 4; ++rg) {
        const int r = wm * 64 + mt * 16 + quad * 4 + rg;
        const long idx = (row0 + r) * 128 + c;
        out[idx] = (acc[mt][nt][rg] + bz) * bs2f(g_in[idx]);
      }
  }
}

extern "C" void kernel_launch(void* const* d_in, const int* in_sizes, int n_in,
                              void* d_out, int out_size, void* d_ws, size_t ws_size,
                              hipStream_t stream) {
  const float* z = (const float*)d_in[0];
  const float* mask = (const float*)d_in[1];
  const float* w_ab_p = (const float*)d_in[2];
  const float* b_ab_p = (const float*)d_in[3];
  const float* w_ab_g = (const float*)d_in[4];
  const float* b_ab_g = (const float*)d_in[5];
  const float* w_g = (const float*)d_in[6];
  const float* b_g = (const float*)d_in[7];
  const float* w_z = (const float*)d_in[8];
  const float* b_z = (const float*)d_in[9];
  const float* ln_in_g = (const float*)d_in[10];
  const float* ln_in_b = (const float*)d_in[11];
  const float* ln_out_g = (const float*)d_in[12];
  const float* ln_out_b = (const float*)d_in[13];
  float* out = (float*)d_out;

  // workspace (all bf16 u16): a_t, b_t, x_t, g (4 * 64 MB) + wb (160 KB)
  u16* a_t = (u16*)d_ws;
  u16* b_t = a_t + (size_t)RR * 128;
  u16* x_t = b_t + (size_t)RR * 128;
  u16* g_b = x_t + (size_t)RR * 128;
  u16* wb = g_b + (size_t)RR * 128;

  k_wconv<<<80, 256, 0, stream>>>(w_ab_p, w_ab_g, w_g, wb);
  k_proj<<<RR / 128, 256, 0, stream>>>(z, mask, wb, b_ab_p, b_ab_g, b_g,
                                       ln_in_g, ln_in_b, a_t, b_t, g_b);
  k_tri<<<dim3(16, 128), 256, 0, stream>>>(a_t, b_t, x_t);
  k_out<<<RR / 128, 256, 0, stream>>>(x_t, w_z, b_z, ln_out_g, ln_out_b, g_b, out);
}